// Round 14
// baseline (235.723 us; speedup 1.0000x reference)
//
#include <hip/hip_runtime.h>

// DynamicMaskHead v6: two-kernel split (logits -> d_ws, then upsample).
// Rationale: v1..v5 fused variants plateau at ~82-83us kernel time vs
// max(VALU 19us, write 25us) floors. v3's counters (VALUBusy 88.5%, ~13k
// VALU inst/thread vs ~1.2k ideal) showed hipcc bloats the complex fused
// kernel; occupancy (v2,v5) and LDS-inst (v4) levers were ~neutral.
// Split kernels are simple enough to compile lean, with perfectly
// vectorized loads/stores. Falls back to v5 fused if ws_size too small.

#define HH   128
#define WW   192
#define HW   (HH*WW)
#define OHH  256
#define OWW  384
#define NPARAMS 169

// ======================= Kernel A: logits =============================
// grid (24, n_inst), 256 thr. Thread -> 4 consecutive px (one float4).
// Feature loads: 8 coalesced float4. No halo, no clamps.
__global__ __launch_bounds__(256, 4)
void dmh_logits(const float* __restrict__ mask_feats,
                const float* __restrict__ params,
                const float* __restrict__ locs,
                const int*   __restrict__ im_inds,
                const int*   __restrict__ fpn,
                float* __restrict__ lg)          // [n_inst][HW]
{
    // LDS weight layout (as v5): W0^T [10][8] @0, W1 [8][8] @80, W2 @144,
    // b0 @152, b1 @160, b2 @168
    __shared__ float sw[176];
    const int inst = blockIdx.y;
    const int tid  = threadIdx.x;
    if (tid < NPARAMS) {
        const float v = params[(size_t)inst * NPARAMS + tid];
        const int d = (tid < 80) ? (tid % 10) * 8 + (tid / 10) : tid;
        sw[d] = v;
    }
    const int   im     = im_inds[inst];
    const float instx  = locs[2*inst];
    const float insty  = locs[2*inst + 1];
    const float invsoi = 1.0f / (float)(64 << fpn[inst]);
    __syncthreads();

    const int p  = blockIdx.x * 1024 + tid * 4;   // flat px, 4-aligned, same row
    const int gy = p / WW;
    const int gx = p - gy * WW;
    const float ry  = (insty - (float)(gy*8 + 4)) * invsoi;
    const float dx  = 8.0f * invsoi;
    const float rx0 = (instx - (float)(gx*8 + 4)) * invsoi;
    const float rxv[4] = {rx0, rx0 - dx, rx0 - 2.0f*dx, rx0 - 3.0f*dx};

    const float* __restrict__ fp = mask_feats + (size_t)im * 8 * HW + p;

    // ---- layer 0: channel-outer, h0[4][8] accumulators ----
    float h0[4][8];
    {
        float4 A = *(const float4*)&sw[0];
        float4 B = *(const float4*)&sw[4];
#pragma unroll
        for (int k = 0; k < 4; ++k) {
            const float r = rxv[k];
            h0[k][0] = A.x*r; h0[k][1] = A.y*r; h0[k][2] = A.z*r; h0[k][3] = A.w*r;
            h0[k][4] = B.x*r; h0[k][5] = B.y*r; h0[k][6] = B.z*r; h0[k][7] = B.w*r;
        }
        A = *(const float4*)&sw[8];
        B = *(const float4*)&sw[12];
#pragma unroll
        for (int k = 0; k < 4; ++k) {
            h0[k][0] += A.x*ry; h0[k][1] += A.y*ry; h0[k][2] += A.z*ry; h0[k][3] += A.w*ry;
            h0[k][4] += B.x*ry; h0[k][5] += B.y*ry; h0[k][6] += B.z*ry; h0[k][7] += B.w*ry;
        }
#pragma unroll
        for (int cc = 0; cc < 8; ++cc) {
            const float4 xv = *(const float4*)&fp[cc * HW];
            const float xa[4] = {xv.x, xv.y, xv.z, xv.w};
            A = *(const float4*)&sw[(cc+2)*8];
            B = *(const float4*)&sw[(cc+2)*8 + 4];
#pragma unroll
            for (int k = 0; k < 4; ++k) {
                const float x = xa[k];
                h0[k][0] += A.x*x; h0[k][1] += A.y*x; h0[k][2] += A.z*x; h0[k][3] += A.w*x;
                h0[k][4] += B.x*x; h0[k][5] += B.y*x; h0[k][6] += B.z*x; h0[k][7] += B.w*x;
            }
        }
#pragma unroll
        for (int o = 0; o < 8; ++o) {
            const float b = sw[152 + o];
#pragma unroll
            for (int k = 0; k < 4; ++k)
                h0[k][o] = fmaxf(h0[k][o] + b, 0.0f);
        }
    }

    // ---- layer 1: o-outer ----
    float h1[4][8];
#pragma unroll
    for (int o = 0; o < 8; ++o) {
        const float4 A = *(const float4*)&sw[80 + 8*o];
        const float4 B = *(const float4*)&sw[80 + 8*o + 4];
        const float  b = sw[160 + o];
#pragma unroll
        for (int k = 0; k < 4; ++k) {
            float a = A.x*h0[k][0] + A.y*h0[k][1] + A.z*h0[k][2] + A.w*h0[k][3]
                    + B.x*h0[k][4] + B.y*h0[k][5] + B.z*h0[k][6] + B.w*h0[k][7];
            h1[k][o] = fmaxf(a + b, 0.0f);
        }
    }

    // ---- layer 2 + float4 store ----
    {
        const float4 A = *(const float4*)&sw[144];
        const float4 B = *(const float4*)&sw[148];
        const float  b = sw[168];
        float4 r;
        float* pr = (float*)&r;
#pragma unroll
        for (int k = 0; k < 4; ++k) {
            float a = A.x*h1[k][0] + A.y*h1[k][1] + A.z*h1[k][2] + A.w*h1[k][3]
                    + B.x*h1[k][4] + B.y*h1[k][5] + B.z*h1[k][6] + B.w*h1[k][7];
            pr[k] = a + b;
        }
        *(float4*)&lg[(size_t)inst * HW + p] = r;
    }
}

// ======================= Kernel B: upsample ===========================
// grid (64, n_inst), 384 thr. Thread -> one float4 of one output row.
// out[y][x]: yy=max(y-1,0); iy0=yy>>1; fy=(yy&1)*.5; cols tA,tB,tC as fused.
__global__ __launch_bounds__(384)
void dmh_upsample(const float* __restrict__ lg, float* __restrict__ out)
{
    const int inst = blockIdx.y;
    const int tid  = threadIdx.x;
    const int yq   = tid / 96;            // 0..3
    const int xg   = tid - yq * 96;       // 0..95
    const int y    = blockIdx.x * 4 + yq; // 0..255
    const int yy   = (y > 0) ? (y - 1) : 0;
    const int iy0  = yy >> 1;
    const int iy1  = (iy0 + 1 > HH-1) ? (HH-1) : (iy0 + 1);
    const float fy = (yy & 1) ? 0.5f : 0.0f;
    const float g1 = 1.0f - fy;

    const int m  = 2 * xg;                       // center col
    const int cm = (xg > 0) ? (m - 1) : 0;       // clamped col m-1
    const float* __restrict__ r0 = lg + (size_t)inst * HW + (size_t)iy0 * WW;
    const float* __restrict__ r1 = lg + (size_t)inst * HW + (size_t)iy1 * WW;

    const float tA = r0[cm ]*g1 + r1[cm ]*fy;
    const float tB = r0[m  ]*g1 + r1[m  ]*fy;
    const float tC = r0[m+1]*g1 + r1[m+1]*fy;

    float4 r;
    r.x = 0.5f*(tA + tB);
    r.y = tB;
    r.z = 0.5f*(tB + tC);
    r.w = tC;
    *(float4*)(out + (size_t)inst * OHH * OWW + (size_t)y * OWW + xg * 4) = r;
}

// ================== Fallback: v5 fused (proven correct) ===============
#define THY  32
#define TWX  128
#define LR   18
#define LC   66
#define LCP  67
#define NPX  (LR*LC)
#define PXT  5

__global__ __launch_bounds__(256, 4)
void dmh_fused(const float* __restrict__ mask_feats,
               const float* __restrict__ params,
               const float* __restrict__ locs,
               const int*   __restrict__ im_inds,
               const int*   __restrict__ fpn,
               float* __restrict__ out)
{
    __shared__ float sw[176];
    __shared__ float L[LR][LCP];
    const int inst = blockIdx.z;
    const int tid  = threadIdx.x;
    if (tid < NPARAMS) {
        const float v = params[(size_t)inst * NPARAMS + tid];
        const int d = (tid < 80) ? (tid % 10) * 8 + (tid / 10) : tid;
        sw[d] = v;
    }
    const int   im     = im_inds[inst];
    const float instx  = locs[2*inst];
    const float insty  = locs[2*inst + 1];
    const float invsoi = 1.0f / (float)(64 << fpn[inst]);
    const int oy0 = blockIdx.y * THY;
    const int ox0 = blockIdx.x * TWX;
    const int r0  = oy0 >> 1;
    const int c0  = ox0 >> 1;
    __syncthreads();
    const float* __restrict__ fbase = mask_feats + (size_t)im * 8 * HW;
    float rx[PXT], ry[PXT];
    int foff[PXT], pix[PXT];
#pragma unroll
    for (int k = 0; k < PXT; ++k) {
        int p = tid + 256*k;
        if (p > NPX-1) p = NPX-1;
        int lr = p / LC;
        int lc = p - lr*LC;
        pix[k] = lr*LCP + lc;
        int gy = r0 - 1 + lr; gy = gy < 0 ? 0 : (gy > HH-1 ? HH-1 : gy);
        int gx = c0 - 1 + lc; gx = gx < 0 ? 0 : (gx > WW-1 ? WW-1 : gx);
        rx[k] = (instx - (float)(gx*8 + 4)) * invsoi;
        ry[k] = (insty - (float)(gy*8 + 4)) * invsoi;
        foff[k] = gy*WW + gx;
    }
    float h0[PXT][8];
    {
        float4 A = *(const float4*)&sw[0];
        float4 B = *(const float4*)&sw[4];
#pragma unroll
        for (int k = 0; k < PXT; ++k) {
            h0[k][0] = A.x*rx[k]; h0[k][1] = A.y*rx[k]; h0[k][2] = A.z*rx[k]; h0[k][3] = A.w*rx[k];
            h0[k][4] = B.x*rx[k]; h0[k][5] = B.y*rx[k]; h0[k][6] = B.z*rx[k]; h0[k][7] = B.w*rx[k];
        }
        A = *(const float4*)&sw[8];
        B = *(const float4*)&sw[12];
#pragma unroll
        for (int k = 0; k < PXT; ++k) {
            h0[k][0] += A.x*ry[k]; h0[k][1] += A.y*ry[k]; h0[k][2] += A.z*ry[k]; h0[k][3] += A.w*ry[k];
            h0[k][4] += B.x*ry[k]; h0[k][5] += B.y*ry[k]; h0[k][6] += B.z*ry[k]; h0[k][7] += B.w*ry[k];
        }
#pragma unroll
        for (int cc = 0; cc < 8; ++cc) {
            const float* fpp = fbase + cc*HW;
            float xv[PXT];
#pragma unroll
            for (int k = 0; k < PXT; ++k) xv[k] = fpp[foff[k]];
            A = *(const float4*)&sw[(cc+2)*8];
            B = *(const float4*)&sw[(cc+2)*8 + 4];
#pragma unroll
            for (int k = 0; k < PXT; ++k) {
                h0[k][0] += A.x*xv[k]; h0[k][1] += A.y*xv[k]; h0[k][2] += A.z*xv[k]; h0[k][3] += A.w*xv[k];
                h0[k][4] += B.x*xv[k]; h0[k][5] += B.y*xv[k]; h0[k][6] += B.z*xv[k]; h0[k][7] += B.w*xv[k];
            }
        }
#pragma unroll
        for (int o = 0; o < 8; ++o) {
            const float b = sw[152 + o];
#pragma unroll
            for (int k = 0; k < PXT; ++k)
                h0[k][o] = fmaxf(h0[k][o] + b, 0.0f);
        }
    }
    float h1[PXT][8];
#pragma unroll
    for (int o = 0; o < 8; ++o) {
        const float4 A = *(const float4*)&sw[80 + 8*o];
        const float4 B = *(const float4*)&sw[80 + 8*o + 4];
        const float  b = sw[160 + o];
#pragma unroll
        for (int k = 0; k < PXT; ++k) {
            float a = A.x*h0[k][0] + A.y*h0[k][1] + A.z*h0[k][2] + A.w*h0[k][3]
                    + B.x*h0[k][4] + B.y*h0[k][5] + B.z*h0[k][6] + B.w*h0[k][7];
            h1[k][o] = fmaxf(a + b, 0.0f);
        }
    }
    {
        const float4 A = *(const float4*)&sw[144];
        const float4 B = *(const float4*)&sw[148];
        const float  b = sw[168];
#pragma unroll
        for (int k = 0; k < PXT; ++k) {
            float a = A.x*h1[k][0] + A.y*h1[k][1] + A.z*h1[k][2] + A.w*h1[k][3]
                    + B.x*h1[k][4] + B.y*h1[k][5] + B.z*h1[k][6] + B.w*h1[k][7];
            ((float*)L)[pix[k]] = a + b;
        }
    }
    __syncthreads();
    float* __restrict__ obase = out + (size_t)inst * OHH * OWW;
#pragma unroll
    for (int j = 0; j < 4; ++j) {
        const int yl = (tid >> 5) + 8*j;
        const int xq = (tid & 31) * 4;
        const int y  = oy0 + yl;
        const int yy = (y > 0) ? (y - 1) : 0;
        const int iy0 = yy >> 1;
        const float fy = (yy & 1) ? 0.5f : 0.0f;
        const float gy1 = 1.0f - fy;
        const int ly = iy0 - r0 + 1;
        const int lx = xq >> 1;
        float t[3];
#pragma unroll
        for (int i = 0; i < 3; ++i) {
            const float a  = L[ly  ][lx + i];
            const float bb = L[ly+1][lx + i];
            t[i] = a*gy1 + bb*fy;
        }
        float4 r;
        r.x = 0.5f*t[0] + 0.5f*t[1];
        r.y = t[1];
        r.z = 0.5f*t[1] + 0.5f*t[2];
        r.w = t[2];
        *(float4*)(obase + (size_t)y*OWW + ox0 + xq) = r;
    }
}

extern "C" void kernel_launch(void* const* d_in, const int* in_sizes, int n_in,
                              void* d_out, int out_size, void* d_ws, size_t ws_size,
                              hipStream_t stream) {
    const float* mask_feats = (const float*)d_in[0];
    const float* params     = (const float*)d_in[1];
    const float* locs       = (const float*)d_in[2];
    const int*   im_inds    = (const int*)d_in[3];
    const int*   fpn        = (const int*)d_in[4];
    float*       out        = (float*)d_out;
    const int n_inst = in_sizes[1] / NPARAMS;   // 400

    const size_t need = (size_t)n_inst * HW * sizeof(float);   // 39.3 MB
    if (ws_size >= need) {
        float* lg = (float*)d_ws;
        dmh_logits  <<<dim3(24, n_inst), 256, 0, stream>>>(mask_feats, params, locs, im_inds, fpn, lg);
        dmh_upsample<<<dim3(64, n_inst), 384, 0, stream>>>(lg, out);
    } else {
        dmh_fused<<<dim3(OWW/TWX, OHH/THY, n_inst), 256, 0, stream>>>(mask_feats, params, locs, im_inds, fpn, out);
    }
}